// Round 3
// baseline (220.620 us; speedup 1.0000x reference)
//
#include <hip/hip_runtime.h>

// IMM loss: G=8192 groups of M=16 particles, D=64 dims, fp32.
// terms = Lap(x,x)+Lap(y,y)-2*Lap(x,y), Lap = exp(-ws[j]*max(||a-b||,EPS)/D).
//
// R3: offset-split wave pairs. Each 64-lane wave covers 4 groups (lane = gg*16+j);
// within a pair of waves, role A computes full-pair offsets 1-5 + xy offset 9,
// role B computes full-pair offsets 6-8 + xy offsets 0,10-15 + the diagonal.
// Both waves read the same rows (2nd read hits L1/L2). Dims processed in 4
// chunks of 16 to keep VGPRs < 128 -> 4 waves/SIMD (2x R2's TLP).
// dl = x-y precomputed per chunk; ty = tz + dl keeps each DPP single-use so
// GCNDPPCombine can fuse v_mov_dpp into v_sub_f32_dpp.

#define EPS_D 0.006f
#define DIMS 64

// Rotate right within each 16-lane row by O (compile-time constant 1..15):
// lane j receives lane (j+O)&15 of its row. Verified exact in R2 (absmax 0.0).
#define ROT(v, O) __int_as_float(__builtin_amdgcn_update_dpp(              \
        0, __float_as_int(v), 0x120 + (O), 0xF, 0xF, false))

#define FULL_CH(O, I) {                                                    \
    _Pragma("unroll")                                                      \
    for (int d = 0; d < 16; ++d) {                                         \
        float tx = ROT(xd[d], O) - xd[d];   /* xr - x  (single use) */     \
        float tz = ROT(yd[d], O) - xd[d];   /* yr - x  (single use) */     \
        float ty = tz + dl[d];              /* yr - y = (yr-x)+(x-y) */    \
        fxx[I] = fmaf(tx, tx, fxx[I]);                                     \
        fyy[I] = fmaf(ty, ty, fyy[I]);                                     \
        fxy[I] = fmaf(tz, tz, fxy[I]);                                     \
    } }

#define XY_CH(O, I) {                                                      \
    _Pragma("unroll")                                                      \
    for (int d = 0; d < 16; ++d) {                                         \
        float tz = ROT(yd[d], O) - xd[d];                                  \
        gxy[I] = fmaf(tz, tz, gxy[I]);                                     \
    } }

// full-pair epilogue: ordered (j,k) uses s_j, (k,j) uses s_k; o=8 weight 0.5.
#define EPI_FULL(O, I, W) {                                                \
    const float s_k = ROT(s_j, O);                                         \
    const float ddx = fmaxf(sqrtf(fxx[I]), EPS_D);                         \
    const float ddy = fmaxf(sqrtf(fyy[I]), EPS_D);                         \
    const float ddz = fmaxf(sqrtf(fxy[I]), EPS_D);                         \
    acc += (W) * (__expf(-s_j * ddx) + __expf(-s_k * ddx));                \
    acc += (W) * (__expf(-s_j * ddy) + __expf(-s_k * ddy));                \
    acc -= 2.0f * __expf(-s_j * ddz); }

#define EPI_XY(I)                                                          \
    acc -= 2.0f * __expf(-s_j * fmaxf(sqrtf(gxy[I]), EPS_D));

__global__ __launch_bounds__(256, 4)
void imm_loss_kernel(const float* __restrict__ ys_t,
                     const float* __restrict__ ys_r,
                     const float* __restrict__ w_scale,
                     const float* __restrict__ time_w,
                     float* __restrict__ partials)
{
    const int tid  = threadIdx.x;
    const int lane = tid & 63;
    const int wave = tid >> 6;
    const int role = wave & 1;    // 0: full 1-5 + xy 9 | 1: full 6-8 + xy 0,10-15 + diag
    const int pair = wave >> 1;
    const int b    = blockIdx.x * 128 + pair * 64 + lane;  // global row g*16+j

    const float* xrow = ys_t + (size_t)b * DIMS;
    const float* yrow = ys_r + (size_t)b * DIMS;

    const float s_j = w_scale[b] * (1.0f / (float)DIMS);   // ws[j]/D
    const float tw  = time_w[b & ~15];                     // time_weights[g*16]

    float fxx[5] = {0,0,0,0,0}, fyy[5] = {0,0,0,0,0}, fxy[5] = {0,0,0,0,0};
    float gxy[7] = {0,0,0,0,0,0,0};

    #pragma unroll
    for (int c = 0; c < 4; ++c) {
        float xd[16], yd[16], dl[16];
        const float4* xp = reinterpret_cast<const float4*>(xrow + c * 16);
        const float4* yp = reinterpret_cast<const float4*>(yrow + c * 16);
        #pragma unroll
        for (int q = 0; q < 4; ++q) {
            float4 v = xp[q];
            xd[4*q+0] = v.x; xd[4*q+1] = v.y; xd[4*q+2] = v.z; xd[4*q+3] = v.w;
        }
        #pragma unroll
        for (int q = 0; q < 4; ++q) {
            float4 v = yp[q];
            yd[4*q+0] = v.x; yd[4*q+1] = v.y; yd[4*q+2] = v.z; yd[4*q+3] = v.w;
        }
        #pragma unroll
        for (int d = 0; d < 16; ++d) dl[d] = xd[d] - yd[d];

        if (role == 0) {
            FULL_CH(1, 0) FULL_CH(2, 1) FULL_CH(3, 2) FULL_CH(4, 3) FULL_CH(5, 4)
            XY_CH(9, 0)
        } else {
            FULL_CH(6, 0) FULL_CH(7, 1) FULL_CH(8, 2)
            // xy offset 0: partner is local, t = y - x = -dl
            #pragma unroll
            for (int d = 0; d < 16; ++d) gxy[0] = fmaf(dl[d], dl[d], gxy[0]);
            XY_CH(10, 1) XY_CH(11, 2) XY_CH(12, 3)
            XY_CH(13, 4) XY_CH(14, 5) XY_CH(15, 6)
        }
    }

    float acc = 0.f;
    if (role == 0) {
        EPI_FULL(1, 0, 1.0f) EPI_FULL(2, 1, 1.0f) EPI_FULL(3, 2, 1.0f)
        EPI_FULL(4, 3, 1.0f) EPI_FULL(5, 4, 1.0f)
        EPI_XY(0)                                   // xy offset 9
    } else {
        EPI_FULL(6, 0, 1.0f) EPI_FULL(7, 1, 1.0f) EPI_FULL(8, 2, 0.5f)
        acc += 2.0f * __expf(-s_j * EPS_D);         // xx+yy diagonal (d=0 -> EPS)
        EPI_XY(0)                                   // xy offset 0
        EPI_XY(1) EPI_XY(2) EPI_XY(3) EPI_XY(4) EPI_XY(5) EPI_XY(6)  // xy 10-15
    }

    // tw uniform per 16-lane cluster; wave reduce sums 4 groups.
    float val = acc * tw;
    #pragma unroll
    for (int off = 32; off; off >>= 1)
        val += __shfl_xor(val, off, 64);

    __shared__ float smem[4];
    if (lane == 0) smem[wave] = val;
    __syncthreads();
    if (tid == 0)
        partials[blockIdx.x] = smem[0] + smem[1] + smem[2] + smem[3];
}

__global__ void imm_reduce_kernel(const float* __restrict__ part, int n,
                                  float inv_scale, float* __restrict__ out)
{
    const int tid = threadIdx.x;
    float v = 0.f;
    for (int i = tid; i < n; i += 256) v += part[i];
    #pragma unroll
    for (int off = 32; off; off >>= 1) v += __shfl_xor(v, off, 64);
    __shared__ float s[4];
    if ((tid & 63) == 0) s[tid >> 6] = v;
    __syncthreads();
    if (tid == 0) out[0] = (s[0] + s[1] + s[2] + s[3]) * inv_scale;
}

extern "C" void kernel_launch(void* const* d_in, const int* in_sizes, int n_in,
                              void* d_out, int out_size, void* d_ws, size_t ws_size,
                              hipStream_t stream)
{
    const float* ys_t = (const float*)d_in[0];
    const float* ys_r = (const float*)d_in[1];
    const float* wsc  = (const float*)d_in[2];
    const float* twp  = (const float*)d_in[3];
    float* out      = (float*)d_out;
    float* partials = (float*)d_ws;

    const int B = in_sizes[2];      // 131072
    const int G = B / 16;           // 8192 groups
    const int blocks = G / 8;       // 8 groups per block (2 wave-pairs x 4 groups)

    imm_loss_kernel<<<blocks, 256, 0, stream>>>(ys_t, ys_r, wsc, twp, partials);

    const float inv_scale = 1.0f / (256.0f * (float)G);  // 1/(M*M*G)
    imm_reduce_kernel<<<1, 256, 0, stream>>>(partials, blocks, inv_scale, out);
}

// Round 4
// 130.347 us; speedup vs baseline: 1.6926x; 1.6926x over previous
//
#include <hip/hip_runtime.h>

// IMM loss: G=8192 groups of M=16 particles, D=64 dims, fp32.
// terms = Lap(x,x)+Lap(y,y)-2*Lap(x,y), Lap = exp(-ws[j]*max(||a-b||,EPS)/D).
//
// R4: R3's offset-split wave pairs, but __launch_bounds__(256,2).
// R3's (256,4) forced a 64-VGPR allocation (observed VGPR_Count=64) that
// spilled the per-lane state (~90 floats) to scratch: WRITE_SIZE 287 MB,
// FETCH 236 MB, 142 us. Cap 256 lets the allocator take the ~96-128 it
// needs; runtime occupancy is set by the ACTUAL count -> 4 waves/SIMD.
//
// Structure: 1 wave = 4 groups (lane = gg*16+j, DPP row_ror = in-group
// partner rotation). Wave-pair roles: A = full offsets 1-5 + xy 9;
// B = full offsets 6-8 + xy 0,10-15 + diagonal. Dims in 4 chunks of 16.

#define EPS_D 0.006f
#define DIMS 64

// Rotate right within each 16-lane row by O (compile-time 1..15):
// lane j receives lane (j+O)&15. Verified exact (R2/R3 absmax 0.0).
#define ROT(v, O) __int_as_float(__builtin_amdgcn_update_dpp(              \
        0, __float_as_int(v), 0x120 + (O), 0xF, 0xF, false))

#define FULL_CH(O, I) {                                                    \
    _Pragma("unroll")                                                      \
    for (int d = 0; d < 16; ++d) {                                         \
        float tx = ROT(xd[d], O) - xd[d];   /* xr - x  (single use) */     \
        float tz = ROT(yd[d], O) - xd[d];   /* yr - x  (single use) */     \
        float ty = tz + dl[d];              /* yr - y = (yr-x)+(x-y) */    \
        fxx[I] = fmaf(tx, tx, fxx[I]);                                     \
        fyy[I] = fmaf(ty, ty, fyy[I]);                                     \
        fxy[I] = fmaf(tz, tz, fxy[I]);                                     \
    } }

#define XY_CH(O, I) {                                                      \
    _Pragma("unroll")                                                      \
    for (int d = 0; d < 16; ++d) {                                         \
        float tz = ROT(yd[d], O) - xd[d];                                  \
        gxy[I] = fmaf(tz, tz, gxy[I]);                                     \
    } }

// full-pair epilogue: ordered (j,k) uses s_j, (k,j) uses s_k; o=8 weight 0.5.
#define EPI_FULL(O, I, W) {                                                \
    const float s_k = ROT(s_j, O);                                         \
    const float ddx = fmaxf(sqrtf(fxx[I]), EPS_D);                         \
    const float ddy = fmaxf(sqrtf(fyy[I]), EPS_D);                         \
    const float ddz = fmaxf(sqrtf(fxy[I]), EPS_D);                         \
    acc += (W) * (__expf(-s_j * ddx) + __expf(-s_k * ddx));                \
    acc += (W) * (__expf(-s_j * ddy) + __expf(-s_k * ddy));                \
    acc -= 2.0f * __expf(-s_j * ddz); }

#define EPI_XY(I)                                                          \
    acc -= 2.0f * __expf(-s_j * fmaxf(sqrtf(gxy[I]), EPS_D));

__global__ __launch_bounds__(256, 2)   // cap 256 VGPR: no spills (R3 lesson)
void imm_loss_kernel(const float* __restrict__ ys_t,
                     const float* __restrict__ ys_r,
                     const float* __restrict__ w_scale,
                     const float* __restrict__ time_w,
                     float* __restrict__ partials)
{
    const int tid  = threadIdx.x;
    const int lane = tid & 63;
    const int wave = tid >> 6;
    const int role = wave & 1;    // 0: full 1-5 + xy 9 | 1: full 6-8 + xy 0,10-15 + diag
    const int pair = wave >> 1;
    const int b    = blockIdx.x * 128 + pair * 64 + lane;  // global row g*16+j

    const float* xrow = ys_t + (size_t)b * DIMS;
    const float* yrow = ys_r + (size_t)b * DIMS;

    const float s_j = w_scale[b] * (1.0f / (float)DIMS);   // ws[j]/D
    const float tw  = time_w[b & ~15];                     // time_weights[g*16]

    float fxx[5] = {0,0,0,0,0}, fyy[5] = {0,0,0,0,0}, fxy[5] = {0,0,0,0,0};
    float gxy[7] = {0,0,0,0,0,0,0};

    #pragma unroll
    for (int c = 0; c < 4; ++c) {
        float xd[16], yd[16], dl[16];
        const float4* xp = reinterpret_cast<const float4*>(xrow + c * 16);
        const float4* yp = reinterpret_cast<const float4*>(yrow + c * 16);
        #pragma unroll
        for (int q = 0; q < 4; ++q) {
            float4 v = xp[q];
            xd[4*q+0] = v.x; xd[4*q+1] = v.y; xd[4*q+2] = v.z; xd[4*q+3] = v.w;
        }
        #pragma unroll
        for (int q = 0; q < 4; ++q) {
            float4 v = yp[q];
            yd[4*q+0] = v.x; yd[4*q+1] = v.y; yd[4*q+2] = v.z; yd[4*q+3] = v.w;
        }
        #pragma unroll
        for (int d = 0; d < 16; ++d) dl[d] = xd[d] - yd[d];

        if (role == 0) {
            FULL_CH(1, 0) FULL_CH(2, 1) FULL_CH(3, 2) FULL_CH(4, 3) FULL_CH(5, 4)
            XY_CH(9, 0)
        } else {
            FULL_CH(6, 0) FULL_CH(7, 1) FULL_CH(8, 2)
            // xy offset 0: partner is local, t = y - x = -dl
            #pragma unroll
            for (int d = 0; d < 16; ++d) gxy[0] = fmaf(dl[d], dl[d], gxy[0]);
            XY_CH(10, 1) XY_CH(11, 2) XY_CH(12, 3)
            XY_CH(13, 4) XY_CH(14, 5) XY_CH(15, 6)
        }
    }

    float acc = 0.f;
    if (role == 0) {
        EPI_FULL(1, 0, 1.0f) EPI_FULL(2, 1, 1.0f) EPI_FULL(3, 2, 1.0f)
        EPI_FULL(4, 3, 1.0f) EPI_FULL(5, 4, 1.0f)
        EPI_XY(0)                                   // xy offset 9
    } else {
        EPI_FULL(6, 0, 1.0f) EPI_FULL(7, 1, 1.0f) EPI_FULL(8, 2, 0.5f)
        acc += 2.0f * __expf(-s_j * EPS_D);         // xx+yy diagonal (d=0 -> EPS)
        EPI_XY(0)                                   // xy offset 0
        EPI_XY(1) EPI_XY(2) EPI_XY(3) EPI_XY(4) EPI_XY(5) EPI_XY(6)  // xy 10-15
    }

    // tw uniform per 16-lane cluster; wave reduce sums 4 groups.
    float val = acc * tw;
    #pragma unroll
    for (int off = 32; off; off >>= 1)
        val += __shfl_xor(val, off, 64);

    __shared__ float smem[4];
    if (lane == 0) smem[wave] = val;
    __syncthreads();
    if (tid == 0)
        partials[blockIdx.x] = smem[0] + smem[1] + smem[2] + smem[3];
}

__global__ void imm_reduce_kernel(const float* __restrict__ part, int n,
                                  float inv_scale, float* __restrict__ out)
{
    const int tid = threadIdx.x;
    float v = 0.f;
    for (int i = tid; i < n; i += 256) v += part[i];
    #pragma unroll
    for (int off = 32; off; off >>= 1) v += __shfl_xor(v, off, 64);
    __shared__ float s[4];
    if ((tid & 63) == 0) s[tid >> 6] = v;
    __syncthreads();
    if (tid == 0) out[0] = (s[0] + s[1] + s[2] + s[3]) * inv_scale;
}

extern "C" void kernel_launch(void* const* d_in, const int* in_sizes, int n_in,
                              void* d_out, int out_size, void* d_ws, size_t ws_size,
                              hipStream_t stream)
{
    const float* ys_t = (const float*)d_in[0];
    const float* ys_r = (const float*)d_in[1];
    const float* wsc  = (const float*)d_in[2];
    const float* twp  = (const float*)d_in[3];
    float* out      = (float*)d_out;
    float* partials = (float*)d_ws;

    const int B = in_sizes[2];      // 131072
    const int G = B / 16;           // 8192 groups
    const int blocks = G / 8;       // 8 groups per block (2 wave-pairs x 4 groups)

    imm_loss_kernel<<<blocks, 256, 0, stream>>>(ys_t, ys_r, wsc, twp, partials);

    const float inv_scale = 1.0f / (256.0f * (float)G);  // 1/(M*M*G)
    imm_reduce_kernel<<<1, 256, 0, stream>>>(partials, blocks, inv_scale, out);
}

// Round 5
// 118.497 us; speedup vs baseline: 1.8618x; 1.1000x over previous
//
#include <hip/hip_runtime.h>

// IMM loss: G=8192 groups of M=16 particles, D=64 dims, fp32.
// terms = Lap(x,x)+Lap(y,y)-2*Lap(x,y), Lap = exp(-ws[j]*max(||a-b||,EPS)/D).
//
// R5: dim-sliced lane mapping. One wave per group; lane = q*16+j holds dims
// [16q,16q+16) of particle j. A wave's 64 lanes cover one contiguous 4 KB
// block per tensor -> first dwordx4 warms L1, rest hit (R4's 256B-stride
// per-lane pattern scattered each load over 16 KB; loads were the bottleneck).
// Partner (j+o)&15 has the same q -> row_ror DPP still works. 16-dim partial
// distances are butterflied across q with __shfl_xor(16/32); epilogue runs
// redundantly in all 4 q-rows (wave-issued once) and the x4 is folded into
// the final scale. Per-offset partials die immediately -> ~60-70 live VGPRs,
// no spills (R3/R4 lesson: WRITE_SIZE must stay ~KB).

#define EPS_D 0.006f

// Rotate right within each 16-lane row by O (compile-time 1..15):
// lane q*16+j receives lane q*16+((j+O)&15). Verified exact (R2-R4 absmax 0.0).
#define ROT(v, O) __int_as_float(__builtin_amdgcn_update_dpp(              \
        0, __float_as_int(v), 0x120 + (O), 0xF, 0xF, false))

// Sum the 4 q-row partials (lanes j, j+16, j+32, j+48): all lanes get total.
__device__ __forceinline__ float red4(float p) {
    p += __shfl_xor(p, 16, 64);
    p += __shfl_xor(p, 32, 64);
    return p;
}

// Full pair offset: xx & yy via symmetry (ordered (j,k) uses s_j, (k,j) uses
// s_k; o=8 pairs hit from both endpoints -> weight 0.5) + xy at s_j.
#define FULL_O(O, W) {                                                     \
    float pxx = 0.f, pyy = 0.f, pxy = 0.f;                                 \
    _Pragma("unroll")                                                      \
    for (int d = 0; d < 16; ++d) {                                         \
        float tx = ROT(xd[d], O) - xd[d];   /* xr - x (single use) */      \
        float tz = ROT(yd[d], O) - xd[d];   /* yr - x (single use) */      \
        float ty = tz + dl[d];              /* yr - y */                   \
        pxx = fmaf(tx, tx, pxx);                                           \
        pyy = fmaf(ty, ty, pyy);                                           \
        pxy = fmaf(tz, tz, pxy);                                           \
    }                                                                      \
    pxx = red4(pxx);  pyy = red4(pyy);  pxy = red4(pxy);                   \
    const float s_k = ROT(s_j, O);                                         \
    const float ddx = fmaxf(sqrtf(pxx), EPS_D);                            \
    const float ddy = fmaxf(sqrtf(pyy), EPS_D);                            \
    const float ddz = fmaxf(sqrtf(pxy), EPS_D);                            \
    acc += (W) * (__expf(-s_j * ddx) + __expf(-s_k * ddx));                \
    acc += (W) * (__expf(-s_j * ddy) + __expf(-s_k * ddy));                \
    acc -= 2.0f * __expf(-s_j * ddz); }

#define XY_O(O) {                                                          \
    float pxy = 0.f;                                                       \
    _Pragma("unroll")                                                      \
    for (int d = 0; d < 16; ++d) {                                         \
        float tz = ROT(yd[d], O) - xd[d];                                  \
        pxy = fmaf(tz, tz, pxy);                                           \
    }                                                                      \
    pxy = red4(pxy);                                                       \
    acc -= 2.0f * __expf(-s_j * fmaxf(sqrtf(pxy), EPS_D)); }

__global__ __launch_bounds__(256, 4)   // cap 128 VGPR; need ~70 -> no spill
void imm_loss_kernel(const float* __restrict__ ys_t,
                     const float* __restrict__ ys_r,
                     const float* __restrict__ w_scale,
                     const float* __restrict__ time_w,
                     float* __restrict__ partials)
{
    const int tid  = threadIdx.x;
    const int lane = tid & 63;
    const int wave = tid >> 6;
    const int q    = lane >> 4;          // dim slice: dims [16q, 16q+16)
    const int j    = lane & 15;          // particle index
    const int g    = blockIdx.x * 4 + wave;   // group id (8192 total)

    const size_t base = (size_t)g * 1024 + j * 64 + q * 16;
    const float4* xp = reinterpret_cast<const float4*>(ys_t + base);
    const float4* yp = reinterpret_cast<const float4*>(ys_r + base);

    float xd[16], yd[16], dl[16];
    #pragma unroll
    for (int t = 0; t < 4; ++t) {
        float4 v = xp[t];
        xd[4*t+0] = v.x; xd[4*t+1] = v.y; xd[4*t+2] = v.z; xd[4*t+3] = v.w;
    }
    #pragma unroll
    for (int t = 0; t < 4; ++t) {
        float4 v = yp[t];
        yd[4*t+0] = v.x; yd[4*t+1] = v.y; yd[4*t+2] = v.z; yd[4*t+3] = v.w;
    }
    #pragma unroll
    for (int d = 0; d < 16; ++d) dl[d] = xd[d] - yd[d];

    const float s_j = w_scale[g * 16 + j] * (1.0f / 64.0f);  // ws[j]/D
    const float tw  = time_w[g * 16];                        // per-group weight

    // xx + yy diagonals (d=0 clamps to EPS).
    float acc = 2.0f * __expf(-s_j * EPS_D);

    // xy offset 0: t = y - x = -dl (square kills the sign).
    {
        float p0 = 0.f;
        #pragma unroll
        for (int d = 0; d < 16; ++d) p0 = fmaf(dl[d], dl[d], p0);
        p0 = red4(p0);
        acc -= 2.0f * __expf(-s_j * fmaxf(sqrtf(p0), EPS_D));
    }

    FULL_O(1, 1.0f)
    FULL_O(2, 1.0f)
    FULL_O(3, 1.0f)
    FULL_O(4, 1.0f)
    FULL_O(5, 1.0f)
    FULL_O(6, 1.0f)
    FULL_O(7, 1.0f)
    FULL_O(8, 0.5f)
    XY_O(9)
    XY_O(10)
    XY_O(11)
    XY_O(12)
    XY_O(13)
    XY_O(14)
    XY_O(15)

    // acc is replicated across the 4 q-rows; wave sum = 4 * sum_j acc_j.
    // The extra x4 is folded into inv_scale in the reduce kernel.
    float val = acc * tw;
    #pragma unroll
    for (int off = 32; off; off >>= 1)
        val += __shfl_xor(val, off, 64);

    __shared__ float smem[4];
    if (lane == 0) smem[wave] = val;
    __syncthreads();
    if (tid == 0)
        partials[blockIdx.x] = smem[0] + smem[1] + smem[2] + smem[3];
}

__global__ void imm_reduce_kernel(const float* __restrict__ part, int n,
                                  float inv_scale, float* __restrict__ out)
{
    const int tid = threadIdx.x;
    float v = 0.f;
    for (int i = tid; i < n; i += 256) v += part[i];
    #pragma unroll
    for (int off = 32; off; off >>= 1) v += __shfl_xor(v, off, 64);
    __shared__ float s[4];
    if ((tid & 63) == 0) s[tid >> 6] = v;
    __syncthreads();
    if (tid == 0) out[0] = (s[0] + s[1] + s[2] + s[3]) * inv_scale;
}

extern "C" void kernel_launch(void* const* d_in, const int* in_sizes, int n_in,
                              void* d_out, int out_size, void* d_ws, size_t ws_size,
                              hipStream_t stream)
{
    const float* ys_t = (const float*)d_in[0];
    const float* ys_r = (const float*)d_in[1];
    const float* wsc  = (const float*)d_in[2];
    const float* twp  = (const float*)d_in[3];
    float* out      = (float*)d_out;
    float* partials = (float*)d_ws;

    const int B = in_sizes[2];      // 131072
    const int G = B / 16;           // 8192 groups
    const int blocks = G / 4;       // 1 group per wave, 4 waves per block

    imm_loss_kernel<<<blocks, 256, 0, stream>>>(ys_t, ys_r, wsc, twp, partials);

    // 1/(M*M*G) with the extra /4 for the q-row replication of acc.
    const float inv_scale = 1.0f / (4.0f * 256.0f * (float)G);
    imm_reduce_kernel<<<1, 256, 0, stream>>>(partials, blocks, inv_scale, out);
}